// Round 16
// baseline (1061.780 us; speedup 1.0000x reference)
//
#include <hip/hip_runtime.h>
#include <hip/hip_bf16.h>
#include <cstdint>

typedef float  f32x4  __attribute__((ext_vector_type(4)));
typedef __bf16 bf16x8 __attribute__((ext_vector_type(8)));
typedef __bf16 bf16x4 __attribute__((ext_vector_type(4)));
typedef __bf16 bf16x2 __attribute__((ext_vector_type(2)));

#define AS1 __attribute__((address_space(1)))
#define AS3 __attribute__((address_space(3)))

static constexpr int D   = 4096;
static constexpr int SEQ = 2048;
static constexpr int MX  = 4224;   // padded rows: 4096 x-rows + 10 adapter + pad

__device__ __forceinline__ void gload_lds16(const void* g, void* l) {
  __builtin_amdgcn_global_load_lds((AS1 void*)(g), (AS3 void*)(l), 16, 0, 0);
}

__device__ __forceinline__ f32x4 mfma16(bf16x8 a, bf16x8 b, f32x4 c) {
  return __builtin_amdgcn_mfma_f32_16x16x32_bf16(a, b, c, 0, 0, 0);
}

// bijective XCD-chunked remap (m204)
__device__ __forceinline__ int xcd_chunk(int orig, int nwg) {
  int q = nwg >> 3, r = nwg & 7;
  int xcd = orig & 7, pos = orig >> 3;
  return (xcd < r ? xcd * (q + 1) : r * (q + 1) + (xcd - r) * q) + pos;
}

// barrier that is also a compiler memory fence
#define BARF() asm volatile("s_barrier" ::: "memory")

// ---------------------------------------------------------------------------
// transpose + cast x4: W[z] (f32, K x N row-major) -> WT base + z*D*D
__global__ __launch_bounds__(256) void transpose_cast4(const float* __restrict__ w0,
                                                       const float* __restrict__ w1,
                                                       const float* __restrict__ w2,
                                                       const float* __restrict__ w3,
                                                       __bf16* __restrict__ WT) {
  __shared__ float tile[64][65];
  const float* W = (blockIdx.z == 0) ? w0 : (blockIdx.z == 1) ? w1
                 : (blockIdx.z == 2) ? w2 : w3;
  __bf16* dst = WT + (size_t)blockIdx.z * D * D;
  const int t  = threadIdx.x;
  const int r0 = blockIdx.x * 64;
  const int c0 = blockIdx.y * 64;
#pragma unroll
  for (int p = 0; p < 4; ++p) {
    int e = p * 1024 + t * 4;
    int row = e >> 6, col = e & 63;
    f32x4 v = *(const f32x4*)(W + (size_t)(r0 + row) * D + c0 + col);
#pragma unroll
    for (int i = 0; i < 4; ++i) tile[row][col + i] = v[i];
  }
  __syncthreads();
#pragma unroll
  for (int p = 0; p < 2; ++p) {
    int e = p * 2048 + t * 8;
    int orow = e >> 6, ocol = e & 63;
    bf16x8 o;
#pragma unroll
    for (int i = 0; i < 8; ++i) o[i] = (__bf16)tile[ocol + i][orow];
    *(bf16x8*)(dst + (size_t)(c0 + orow) * D + r0 + ocol) = o;
  }
}

// ---------------------------------------------------------------------------
// build xa (bf16, MX x D): rows 0..4095 = x, 4096..4105 = adapter, rest 0
__global__ __launch_bounds__(256) void build_xa(const float* __restrict__ x,
                                                const float* __restrict__ ad,
                                                __bf16* __restrict__ xa) {
  int idx = blockIdx.x * 256 + threadIdx.x;
  int e = idx * 4;
  int row = e >> 12, col = e & 4095;
  f32x4 v = {};
  if (row < 4096)      v = *(const f32x4*)(x + (size_t)row * D + col);
  else if (row < 4106) v = *(const f32x4*)(ad + (size_t)(row - 4096) * D + col);
  bf16x4 o;
#pragma unroll
  for (int i = 0; i < 4; ++i) o[i] = (__bf16)v[i];
  *(bf16x4*)(xa + (size_t)row * D + col) = o;
}

// ---------------------------------------------------------------------------
// 8-phase GEMM, never-drain pipeline (R12 loop — proven best; R13 fused
// epilogue + R15 Q-prescale). MODE 0: fused QKV (RoPE q/k, q pre-scaled,
// v transposed). MODE 1: f32 out.
template <int MODE>
__global__ __launch_bounds__(512, 2) void gemm256(const __bf16* __restrict__ A,
                                                  const __bf16* __restrict__ BT,
                                                  void* __restrict__ O0,
                                                  void* __restrict__ O1,
                                                  void* __restrict__ O2,
                                                  const float* __restrict__ FC,
                                                  const float* __restrict__ FS,
                                                  int Mt) {
  __shared__ __bf16 lds[65536];   // [2 slot][A|B][2 half][128][8 ch][8]
  const int tid = threadIdx.x;
  const int wv = tid >> 6, ln = tid & 63;
  const int lg = ln >> 4, lr = ln & 15;

  const int nwg = gridDim.x;
  const int wgid = xcd_chunk(blockIdx.x, nwg);
  const int m0 = (wgid % Mt) * 256;
  const int n0 = (wgid / Mt) * 256;
  const int wm = (wv >> 2) * 128, wn = (wv & 3) * 64;

  auto stageHalf = [&](int k, int mat, int half) {
    const int slot = k & 1;
    const int kt = k * 64;
    const __bf16* base = mat ? BT + (size_t)(n0 + half * 128) * 4096
                             : A  + (size_t)(m0 + half * 128) * 4096;
#pragma unroll
    for (int i = 0; i < 2; ++i) {
      int c = i * 512 + tid;          // chunk 0..1023
      int r = c >> 3;                 // row-in-half 0..127
      int ch = (c & 7) ^ (r & 7);     // pre-swizzled source k-chunk
      gload_lds16(base + (size_t)r * 4096 + kt + ch * 8,
                  lds + slot * 32768 + mat * 16384 + half * 8192 +
                      (i * 512 + wv * 64) * 8);
    }
  };

  f32x4 acc[8][4] = {};
  bf16x8 aLo[4][2], aHi[4][2], bLo[2][2], bHi[2][2];

  auto rdA = [&](const __bf16* pA, int mi, int kk) -> bf16x8 {
    int r = wm + mi * 16 + lr;
    int R = r & 127;
    int cw = (kk * 4 + lg) ^ (R & 7);
    return *(const bf16x8*)(pA + (r >> 7) * 8192 + R * 64 + cw * 8);
  };
  auto rdB = [&](const __bf16* pB, int ni, int kk) -> bf16x8 {
    int n = wn + ni * 16 + lr;
    int R = n & 127;
    int cw = (kk * 4 + lg) ^ (R & 7);
    return *(const bf16x8*)(pB + (n >> 7) * 8192 + R * 64 + cw * 8);
  };

  // prologue: 6 half-tiles (12 loads outstanding)
  stageHalf(0, 0, 0);
  stageHalf(0, 1, 0);
  stageHalf(0, 0, 1);
  stageHalf(0, 1, 1);
  stageHalf(1, 0, 0);
  stageHalf(1, 1, 0);

  for (int k = 0; k < 63; ++k) {
    const int slot = k & 1;
    const __bf16* pA = lds + slot * 32768;
    const __bf16* pB = lds + slot * 32768 + 16384;

    // ---- P0: stage A.hi(k+1); vmcnt(8); quad LoLo
    stageHalf(k + 1, 0, 1);
    asm volatile("s_waitcnt vmcnt(8)" ::: "memory");
    BARF();
#pragma unroll
    for (int mi = 0; mi < 4; ++mi)
#pragma unroll
      for (int kk = 0; kk < 2; ++kk) aLo[mi][kk] = rdA(pA, mi, kk);
#pragma unroll
    for (int ni = 0; ni < 2; ++ni)
#pragma unroll
      for (int kk = 0; kk < 2; ++kk) bLo[ni][kk] = rdB(pB, ni, kk);
    __builtin_amdgcn_s_setprio(1);
#pragma unroll
    for (int kk = 0; kk < 2; ++kk)
#pragma unroll
      for (int mi = 0; mi < 4; ++mi)
#pragma unroll
        for (int ni = 0; ni < 2; ++ni)
          acc[mi][ni] = mfma16(aLo[mi][kk], bLo[ni][kk], acc[mi][ni]);
    __builtin_amdgcn_s_setprio(0);
    BARF();

    // ---- P1: stage B.hi(k+1); hoisted aHi reads; vmcnt(8)
    stageHalf(k + 1, 1, 1);
#pragma unroll
    for (int mi = 0; mi < 4; ++mi)
#pragma unroll
      for (int kk = 0; kk < 2; ++kk) aHi[mi][kk] = rdA(pA, mi + 4, kk);
    asm volatile("s_waitcnt vmcnt(8)" ::: "memory");
    BARF();
    __builtin_amdgcn_s_setprio(1);
#pragma unroll
    for (int kk = 0; kk < 2; ++kk)
#pragma unroll
      for (int mi = 0; mi < 4; ++mi)
#pragma unroll
        for (int ni = 0; ni < 2; ++ni)
          acc[mi + 4][ni] = mfma16(aHi[mi][kk], bLo[ni][kk], acc[mi + 4][ni]);
    __builtin_amdgcn_s_setprio(0);
    BARF();

    // ---- P2: stage A.lo(k+2); hoisted bHi reads; quad HiHi
    if (k + 2 < 64) stageHalf(k + 2, 0, 0);
#pragma unroll
    for (int ni = 0; ni < 2; ++ni)
#pragma unroll
      for (int kk = 0; kk < 2; ++kk) bHi[ni][kk] = rdB(pB, ni + 2, kk);
    BARF();
    __builtin_amdgcn_s_setprio(1);
#pragma unroll
    for (int kk = 0; kk < 2; ++kk)
#pragma unroll
      for (int mi = 0; mi < 4; ++mi)
#pragma unroll
        for (int ni = 0; ni < 2; ++ni)
          acc[mi + 4][ni + 2] = mfma16(aHi[mi][kk], bHi[ni][kk], acc[mi + 4][ni + 2]);
    __builtin_amdgcn_s_setprio(0);
    BARF();

    // ---- P3: stage B.lo(k+2); quad LoHi (aLo registers still valid)
    if (k + 2 < 64) stageHalf(k + 2, 1, 0);
    BARF();
    __builtin_amdgcn_s_setprio(1);
#pragma unroll
    for (int kk = 0; kk < 2; ++kk)
#pragma unroll
      for (int mi = 0; mi < 4; ++mi)
#pragma unroll
        for (int ni = 0; ni < 2; ++ni)
          acc[mi][ni + 2] = mfma16(aLo[mi][kk], bHi[ni][kk], acc[mi][ni + 2]);
    __builtin_amdgcn_s_setprio(0);
    BARF();
  }

  // ---- tile 63 peeled
  {
    const __bf16* pA = lds + (63 & 1) * 32768;
    const __bf16* pB = lds + (63 & 1) * 32768 + 16384;
    asm volatile("s_waitcnt vmcnt(0)" ::: "memory");
    BARF();
#pragma unroll
    for (int mi = 0; mi < 4; ++mi)
#pragma unroll
      for (int kk = 0; kk < 2; ++kk) aLo[mi][kk] = rdA(pA, mi, kk);
#pragma unroll
    for (int ni = 0; ni < 2; ++ni)
#pragma unroll
      for (int kk = 0; kk < 2; ++kk) bLo[ni][kk] = rdB(pB, ni, kk);
#pragma unroll
    for (int kk = 0; kk < 2; ++kk)
#pragma unroll
      for (int mi = 0; mi < 4; ++mi)
#pragma unroll
        for (int ni = 0; ni < 2; ++ni)
          acc[mi][ni] = mfma16(aLo[mi][kk], bLo[ni][kk], acc[mi][ni]);
#pragma unroll
    for (int mi = 0; mi < 4; ++mi)
#pragma unroll
      for (int kk = 0; kk < 2; ++kk) aHi[mi][kk] = rdA(pA, mi + 4, kk);
#pragma unroll
    for (int ni = 0; ni < 2; ++ni)
#pragma unroll
      for (int kk = 0; kk < 2; ++kk) bHi[ni][kk] = rdB(pB, ni + 2, kk);
#pragma unroll
    for (int kk = 0; kk < 2; ++kk)
#pragma unroll
      for (int mi = 0; mi < 4; ++mi)
#pragma unroll
        for (int ni = 0; ni < 2; ++ni) {
          acc[mi + 4][ni]     = mfma16(aHi[mi][kk], bLo[ni][kk], acc[mi + 4][ni]);
          acc[mi + 4][ni + 2] = mfma16(aHi[mi][kk], bHi[ni][kk], acc[mi + 4][ni + 2]);
          acc[mi][ni + 2]     = mfma16(aLo[mi][kk], bHi[ni][kk], acc[mi][ni + 2]);
        }
  }

  // ---- epilogue
  if constexpr (MODE == 0) {
    const int sel = n0 >> 12;                 // 0=q, 1=k, 2=v
    const int colb = n0 & 4095;
    if (sel < 2) {
      const float qs = sel ? 1.0f : 0.08838834764831845f;
      __bf16* out = sel ? (__bf16*)O1 : (__bf16*)O0;
#pragma unroll
      for (int mi = 0; mi < 8; ++mi)
#pragma unroll
        for (int j = 0; j < 4; ++j) {
          int row = m0 + wm + mi * 16 + lg * 4 + j;
          int s = row & (SEQ - 1);
#pragma unroll
          for (int ni = 0; ni < 4; ++ni) {
            int col = colb + wn + ni * 16 + lr;
            int fi = (col & 127) >> 1;
            float c  = FC[s * 64 + fi];
            float sn = FS[s * 64 + fi];
            float v = acc[mi][ni][j];
            float p = __shfl_xor(v, 1);
            float o = (lr & 1) ? (p * sn + v * c) : (v * c - p * sn);
            out[(size_t)row * 4096 + col] = (__bf16)(o * qs);
          }
        }
    } else {
      __bf16* vT = (__bf16*)O2;
#pragma unroll
      for (int mi = 0; mi < 8; ++mi) {
        int row0 = m0 + wm + mi * 16 + lg * 4;
#pragma unroll
        for (int ni = 0; ni < 4; ++ni) {
          int col = colb + wn + ni * 16 + lr;
          bf16x4 pk;
#pragma unroll
          for (int j = 0; j < 4; ++j) pk[j] = (__bf16)acc[mi][ni][j];
          *(bf16x4*)(vT + (size_t)col * MX + row0) = pk;
        }
      }
    }
  } else {
    float* out = (float*)O0;
#pragma unroll
    for (int mi = 0; mi < 8; ++mi)
#pragma unroll
      for (int ni = 0; ni < 4; ++ni)
#pragma unroll
        for (int j = 0; j < 4; ++j) {
          int row = m0 + wm + mi * 16 + lg * 4 + j;
          int col = n0 + wn + ni * 16 + lr;
          out[(size_t)row * 4096 + col] = acc[mi][ni][j];
        }
  }
}

// ---------------------------------------------------------------------------
// Adapter mini-GEMM: rows 4096..4111 = [adapter;pad] @ [wk|wv].
// K -> kb rows (no RoPE); V -> vT transposed.
__global__ __launch_bounds__(256) void gemm_adapter(const __bf16* __restrict__ xa,
                                                    const __bf16* __restrict__ BT,
                                                    __bf16* __restrict__ kb,
                                                    __bf16* __restrict__ vT) {
  const int tid = threadIdx.x;
  const int wv = tid >> 6, ln = tid & 63;
  const int lg = ln >> 4, lr = ln & 15;
  const int col0 = blockIdx.x * 256 + wv * 64;
  f32x4 acc[4] = {};
  for (int kt = 0; kt < 4096; kt += 32) {
    bf16x8 a = *(const bf16x8*)(xa + (size_t)(4096 + lr) * 4096 + kt + lg * 8);
#pragma unroll
    for (int ni = 0; ni < 4; ++ni) {
      bf16x8 b = *(const bf16x8*)(BT + (size_t)(col0 + ni * 16 + lr) * 4096 +
                                  kt + lg * 8);
      acc[ni] = mfma16(a, b, acc[ni]);
    }
  }
#pragma unroll
  for (int ni = 0; ni < 4; ++ni)
#pragma unroll
    for (int j = 0; j < 4; ++j) {
      int row = 4096 + lg * 4 + j;
      int col = col0 + ni * 16 + lr;
      if (col < 4096) kb[(size_t)row * 4096 + col] = (__bf16)acc[ni][j];
      else            vT[(size_t)(col & 4095) * MX + row] = (__bf16)acc[ni][j];
    }
}

// ---------------------------------------------------------------------------
// Flash attention + adapter (R16): one q-tile per block, 1024 blocks with
// heavy-first XCD-chunked order (dynamic balancing); K staged (dbuf LDS,
// counted vmcnt(4)); V read DIRECT from vT (pattern proven in adapter
// branch) -> LDS 48KB -> 3 blocks/CU (12 waves) for latency hiding.
// Q pre-scaled by 1/sqrt(128) in QKV epilogue.
__global__ __launch_bounds__(256, 3) void attn_kernel(const __bf16* __restrict__ Q,
                                                      const __bf16* __restrict__ K,
                                                      const __bf16* __restrict__ VT,
                                                      const float* __restrict__ gate,
                                                      __bf16* __restrict__ Out) {
  __shared__ __bf16 Ks[2][64 * 128];   // 32 KB
  __shared__ __bf16 Ps[4][32 * 64];    // 16 KB

  const int tid = threadIdx.x;
  const int wv = tid >> 6, ln = tid & 63;
  const int lg = ln >> 4, lr = ln & 15;

  const int wgid = xcd_chunk(blockIdx.x, 1024);
  const int qt = 15 - (wgid & 15);     // heavy first within each XCD chunk
  const int hb = wgid >> 4;
  const int h = hb & 31, b = hb >> 5;

  const float g = tanhf(gate[h]);

  // stage K-tile t: 4 gload_lds16 per thread
  auto stage = [&](int t, int buf) {
    const int kv0 = t * 64;
#pragma unroll
    for (int j = 0; j < 4; ++j) {
      int c = wv * 256 + j * 64 + ln;
      int rk = c >> 4, sck = (c & 15) ^ (rk & 7);
      gload_lds16(K + (size_t)(b * SEQ + kv0 + rk) * D + h * 128 + sck * 8,
                  Ks[buf] + (wv * 256 + j * 64) * 8);
    }
  };

  const int q0 = qt * 128;
  const int qbase = b * SEQ + q0 + wv * 32;

  bf16x8 qf[2][4];
#pragma unroll
  for (int mi = 0; mi < 2; ++mi)
#pragma unroll
    for (int kd = 0; kd < 4; ++kd)
      qf[mi][kd] = *(const bf16x8*)(Q + (size_t)(qbase + mi * 16 + lr) * D +
                                    h * 128 + kd * 32 + lg * 8);

  f32x4 O[2][8] = {};
  float mI2[2], lI2[2];
#pragma unroll
  for (int mi = 0; mi < 2; ++mi) { mI2[mi] = -1e30f; lI2[mi] = 0.f; }

  const int ntiles = 2 * qt + 2;
  stage(0, 0);

  for (int t = 0; t < ntiles; ++t) {
    const int cur = t & 1;
    const int kv0 = t * 64;
    if (t + 1 < ntiles) {
      stage(t + 1, cur ^ 1);
      asm volatile("s_waitcnt vmcnt(4)" ::: "memory");
    } else {
      asm volatile("s_waitcnt vmcnt(0)" ::: "memory");
    }
    __builtin_amdgcn_s_barrier();
    __builtin_amdgcn_sched_barrier(0);

    // ---- QK^T swapped: S[mi][nf] holds S^T fragment (q pre-scaled)
    f32x4 S[2][4] = {};
    __builtin_amdgcn_s_setprio(1);
#pragma unroll
    for (int kd = 0; kd < 4; ++kd) {
      bf16x8 kf[4];
#pragma unroll
      for (int nf = 0; nf < 4; ++nf) {
        int kr = nf * 16 + lr;
        kf[nf] = *(const bf16x8*)(Ks[cur] + kr * 128 +
                                  (((kd * 4 + lg) ^ (kr & 7)) * 8));
      }
#pragma unroll
      for (int mi = 0; mi < 2; ++mi)
#pragma unroll
        for (int nf = 0; nf < 4; ++nf)
          S[mi][nf] = mfma16(kf[nf], qf[mi][kd], S[mi][nf]);
    }
    __builtin_amdgcn_s_setprio(0);

    // ---- in-lane softmax
    float r2[2]; int grew = 0;
#pragma unroll
    for (int mi = 0; mi < 2; ++mi) {
      const int qg = q0 + wv * 32 + mi * 16 + lr;
      float mo = mI2[mi];
      float mt = -3e38f;
#pragma unroll
      for (int nf = 0; nf < 4; ++nf)
#pragma unroll
        for (int j = 0; j < 4; ++j) {
          int kvg = kv0 + nf * 16 + lg * 4 + j;
          float s = S[mi][nf][j];
          s = (kvg > qg) ? -1e30f : s;
          S[mi][nf][j] = s;
          mt = fmaxf(mt, s);
        }
      mt = fmaxf(mt, __shfl_xor(mt, 16));
      mt = fmaxf(mt, __shfl_xor(mt, 32));
      float mn = fmaxf(mo, mt);
      float ps = 0.f;
#pragma unroll
      for (int nf = 0; nf < 4; ++nf)
#pragma unroll
        for (int j = 0; j < 4; ++j) {
          float p = __expf(S[mi][nf][j] - mn);
          S[mi][nf][j] = p;
          ps += p;
        }
      ps += __shfl_xor(ps, 16);
      ps += __shfl_xor(ps, 32);
      float r = __expf(mo - mn);
      lI2[mi] = lI2[mi] * r + ps;
      mI2[mi] = mn;
      r2[mi] = r;
      grew |= (mn > mo) ? 1 : 0;
    }
    if (__any(grew)) {
#pragma unroll
      for (int mi = 0; mi < 2; ++mi)
#pragma unroll
        for (int j = 0; j < 4; ++j) {
          float rj = __shfl(r2[mi], lg * 4 + j);
#pragma unroll
          for (int n = 0; n < 8; ++n) O[mi][n][j] *= rj;
        }
    }

    // ---- P -> bf16x4 packed stores (per-wave LDS, no barrier)
#pragma unroll
    for (int mi = 0; mi < 2; ++mi) {
      int q = mi * 16 + lr;
#pragma unroll
      for (int nf = 0; nf < 4; ++nf) {
        int kv = nf * 16 + lg * 4;
        bf16x4 pk;
#pragma unroll
        for (int j = 0; j < 4; ++j) pk[j] = (__bf16)S[mi][nf][j];
        *(bf16x4*)(Ps[wv] + q * 64 + (((kv >> 3) ^ (q & 7)) * 8) + (kv & 7)) = pk;
      }
    }

    // ---- PV: P from per-wave LDS, V direct from vT (global)
    __builtin_amdgcn_s_setprio(1);
#pragma unroll
    for (int kkv = 0; kkv < 2; ++kkv) {
      bf16x8 pf[2];
#pragma unroll
      for (int mi = 0; mi < 2; ++mi) {
        int prw = mi * 16 + lr;
        pf[mi] = *(const bf16x8*)(Ps[wv] + prw * 64 +
                                  (((kkv * 4 + lg) ^ (prw & 7)) * 8));
      }
#pragma unroll
      for (int n = 0; n < 8; ++n) {
        bf16x8 vf = *(const bf16x8*)(VT + (size_t)(h * 128 + n * 16 + lr) * MX +
                                     b * SEQ + kv0 + kkv * 32 + lg * 8);
#pragma unroll
        for (int mi = 0; mi < 2; ++mi) O[mi][n] = mfma16(pf[mi], vf, O[mi][n]);
      }
    }
    __builtin_amdgcn_s_setprio(0);

    __builtin_amdgcn_s_barrier();   // Ks buf reuse fence
    __builtin_amdgcn_sched_barrier(0);
  }

  // ---- normalize
#pragma unroll
  for (int mi = 0; mi < 2; ++mi) {
    float inv = 1.0f / lI2[mi];
#pragma unroll
    for (int j = 0; j < 4; ++j) {
      float invj = __shfl(inv, lg * 4 + j);
#pragma unroll
      for (int n = 0; n < 8; ++n) O[mi][n][j] *= invj;
    }
  }

  // ---- adapter branch (direct global K and V)
  {
    f32x4 Sa[2] = {};
#pragma unroll
    for (int kd = 0; kd < 4; ++kd) {
      bf16x8 kfa = *(const bf16x8*)(K + (size_t)(2 * SEQ + lr) * D +
                                    h * 128 + kd * 32 + lg * 8);
#pragma unroll
      for (int mi = 0; mi < 2; ++mi) Sa[mi] = mfma16(kfa, qf[mi][kd], Sa[mi]);
    }
#pragma unroll
    for (int mi = 0; mi < 2; ++mi) {
      float mt = -3e38f;
#pragma unroll
      for (int j = 0; j < 4; ++j) {
        int kv = lg * 4 + j;
        float s = Sa[mi][j];
        s = (kv >= 10) ? -1e30f : s;
        Sa[mi][j] = s;
        mt = fmaxf(mt, s);
      }
      mt = fmaxf(mt, __shfl_xor(mt, 16));
      mt = fmaxf(mt, __shfl_xor(mt, 32));
      float ps = 0.f;
#pragma unroll
      for (int j = 0; j < 4; ++j) {
        float p = __expf(Sa[mi][j] - mt);
        Sa[mi][j] = p;
        ps += p;
      }
      ps += __shfl_xor(ps, 16);
      ps += __shfl_xor(ps, 32);
      float gs = g / ps;
      int q = mi * 16 + lr;
      int kv = lg * 4;
      bf16x4 pk, z = {};
#pragma unroll
      for (int j = 0; j < 4; ++j) pk[j] = (__bf16)(Sa[mi][j] * gs);
      *(bf16x4*)(Ps[wv] + q * 64 + (((kv >> 3) ^ (q & 7)) * 8) + (kv & 7)) = pk;
      int kv2 = 16 + kv;
      *(bf16x4*)(Ps[wv] + q * 64 + (((kv2 >> 3) ^ (q & 7)) * 8) + (kv2 & 7)) = z;
    }
    bf16x8 pfa[2];
#pragma unroll
    for (int mi = 0; mi < 2; ++mi) {
      int prw = mi * 16 + lr;
      pfa[mi] = *(const bf16x8*)(Ps[wv] + prw * 64 + ((lg ^ (prw & 7)) * 8));
    }
#pragma unroll
    for (int n = 0; n < 8; ++n) {
      bf16x8 vfa = *(const bf16x8*)(VT + (size_t)(h * 128 + n * 16 + lr) * MX +
                                    2 * SEQ + lg * 8);
#pragma unroll
      for (int mi = 0; mi < 2; ++mi) O[mi][n] = mfma16(pfa[mi], vfa, O[mi][n]);
    }
  }

  // ---- write out
#pragma unroll
  for (int mi = 0; mi < 2; ++mi)
#pragma unroll
    for (int n = 0; n < 8; ++n)
#pragma unroll
      for (int j = 0; j < 4; ++j)
        Out[(size_t)(qbase + mi * 16 + lg * 4 + j) * D + h * 128 + n * 16 + lr] =
            (__bf16)O[mi][n][j];
}

// ---------------------------------------------------------------------------
extern "C" void kernel_launch(void* const* d_in, const int* in_sizes, int n_in,
                              void* d_out, int out_size, void* d_ws, size_t ws_size,
                              hipStream_t stream) {
  const float* x    = (const float*)d_in[0];
  const float* wq   = (const float*)d_in[1];
  const float* wk   = (const float*)d_in[2];
  const float* wv   = (const float*)d_in[3];
  const float* wo   = (const float*)d_in[4];
  const float* gate = (const float*)d_in[5];
  const float* ad   = (const float*)d_in[6];
  const float* fc   = (const float*)d_in[7];
  const float* fs   = (const float*)d_in[8];

  const size_t WSZ = (size_t)D * D * 2;     // 33,554,432
  const size_t XSZ = (size_t)MX * D * 2;    // 34,603,008
  if (ws_size < 4 * WSZ + XSZ + WSZ + 3 * XSZ) return;  // 306,184,192 needed

  char* w = (char*)d_ws;
  size_t off = 0;
  auto alloc = [&](size_t sz) { void* p = w + off; off += sz; return p; };
  __bf16* wqT = (__bf16*)alloc(WSZ);   // wqT/wkT/wvT contiguous = fused 12288xK B^T
  __bf16* wkT = (__bf16*)alloc(WSZ);
  __bf16* wvT = (__bf16*)alloc(WSZ);
  __bf16* woT = (__bf16*)alloc(WSZ);
  __bf16* xa  = (__bf16*)alloc(XSZ);
  __bf16* qb  = (__bf16*)alloc(WSZ);
  __bf16* kb  = (__bf16*)alloc(XSZ);
  __bf16* vb  = (__bf16*)alloc(XSZ);   // scratch; used as attention output
  __bf16* vT  = (__bf16*)alloc(XSZ);
  __bf16* attn = vb;
  (void)wvT;

  dim3 blk(256);
  transpose_cast4<<<dim3(64, 64, 4), blk, 0, stream>>>(wq, wk, wv, wo, wqT);
  build_xa<<<dim3(16896), blk, 0, stream>>>(x, ad, xa);

  // fused QKV GEMM (rope+qscale fused q/k, transposed v): 16x48 = 768 = 3x256.
  gemm256<0><<<dim3(16 * 48), dim3(512), 0, stream>>>(xa, wqT, qb, kb, vT,
                                                      fc, fs, 16);
  // adapter rows 4096..4111: K -> kb rows (no RoPE), V -> vT transposed.
  gemm_adapter<<<dim3(32), blk, 0, stream>>>(xa, wkT, kb, vT);

  attn_kernel<<<dim3(1024), blk, 0, stream>>>(qb, kb, vT, gate, attn);

  gemm256<1><<<dim3(16 * 16), dim3(512), 0, stream>>>(attn, woT, d_out,
                                                      nullptr, nullptr,
                                                      nullptr, nullptr, 16);
}

// Round 17
// 818.041 us; speedup vs baseline: 1.2980x; 1.2980x over previous
//
#include <hip/hip_runtime.h>
#include <hip/hip_bf16.h>
#include <cstdint>

typedef float  f32x4  __attribute__((ext_vector_type(4)));
typedef __bf16 bf16x8 __attribute__((ext_vector_type(8)));
typedef __bf16 bf16x4 __attribute__((ext_vector_type(4)));
typedef __bf16 bf16x2 __attribute__((ext_vector_type(2)));

#define AS1 __attribute__((address_space(1)))
#define AS3 __attribute__((address_space(3)))

static constexpr int D   = 4096;
static constexpr int SEQ = 2048;
static constexpr int MX  = 4224;   // padded rows: 4096 x-rows + 10 adapter + pad

__device__ __forceinline__ void gload_lds16(const void* g, void* l) {
  __builtin_amdgcn_global_load_lds((AS1 void*)(g), (AS3 void*)(l), 16, 0, 0);
}

__device__ __forceinline__ f32x4 mfma16(bf16x8 a, bf16x8 b, f32x4 c) {
  return __builtin_amdgcn_mfma_f32_16x16x32_bf16(a, b, c, 0, 0, 0);
}

// bijective XCD-chunked remap (m204)
__device__ __forceinline__ int xcd_chunk(int orig, int nwg) {
  int q = nwg >> 3, r = nwg & 7;
  int xcd = orig & 7, pos = orig >> 3;
  return (xcd < r ? xcd * (q + 1) : r * (q + 1) + (xcd - r) * q) + pos;
}

// barrier that is also a compiler memory fence
#define BARF() asm volatile("s_barrier" ::: "memory")

// ---------------------------------------------------------------------------
// transpose + cast x4: W[z] (f32, K x N row-major) -> WT base + z*D*D
__global__ __launch_bounds__(256) void transpose_cast4(const float* __restrict__ w0,
                                                       const float* __restrict__ w1,
                                                       const float* __restrict__ w2,
                                                       const float* __restrict__ w3,
                                                       __bf16* __restrict__ WT) {
  __shared__ float tile[64][65];
  const float* W = (blockIdx.z == 0) ? w0 : (blockIdx.z == 1) ? w1
                 : (blockIdx.z == 2) ? w2 : w3;
  __bf16* dst = WT + (size_t)blockIdx.z * D * D;
  const int t  = threadIdx.x;
  const int r0 = blockIdx.x * 64;
  const int c0 = blockIdx.y * 64;
#pragma unroll
  for (int p = 0; p < 4; ++p) {
    int e = p * 1024 + t * 4;
    int row = e >> 6, col = e & 63;
    f32x4 v = *(const f32x4*)(W + (size_t)(r0 + row) * D + c0 + col);
#pragma unroll
    for (int i = 0; i < 4; ++i) tile[row][col + i] = v[i];
  }
  __syncthreads();
#pragma unroll
  for (int p = 0; p < 2; ++p) {
    int e = p * 2048 + t * 8;
    int orow = e >> 6, ocol = e & 63;
    bf16x8 o;
#pragma unroll
    for (int i = 0; i < 8; ++i) o[i] = (__bf16)tile[ocol + i][orow];
    *(bf16x8*)(dst + (size_t)(c0 + orow) * D + r0 + ocol) = o;
  }
}

// ---------------------------------------------------------------------------
// build xa (bf16, MX x D): rows 0..4095 = x, 4096..4105 = adapter, rest 0
__global__ __launch_bounds__(256) void build_xa(const float* __restrict__ x,
                                                const float* __restrict__ ad,
                                                __bf16* __restrict__ xa) {
  int idx = blockIdx.x * 256 + threadIdx.x;
  int e = idx * 4;
  int row = e >> 12, col = e & 4095;
  f32x4 v = {};
  if (row < 4096)      v = *(const f32x4*)(x + (size_t)row * D + col);
  else if (row < 4106) v = *(const f32x4*)(ad + (size_t)(row - 4096) * D + col);
  bf16x4 o;
#pragma unroll
  for (int i = 0; i < 4; ++i) o[i] = (__bf16)v[i];
  *(bf16x4*)(xa + (size_t)row * D + col) = o;
}

// ---------------------------------------------------------------------------
// 8-phase GEMM, never-drain pipeline (R12 loop — proven best; R13 fused
// epilogue + R15 Q-prescale). Loop: tile k stages {A.hi(k+1)@P0,
// B.hi(k+1)@P1, A.lo(k+2)@P2, B.lo(k+2)@P3}; waits vmcnt(8) at P0/P1 only;
// tile 63 peeled vmcnt(0). MODE 0 epilogue: q panel scaled by 1/sqrt(128)
// then RoPE (rope is linear) on f32 acc; k panel RoPE; v panel stored
// TRANSPOSED to vT. MODE 1: f32 out.
template <int MODE>
__global__ __launch_bounds__(512, 2) void gemm256(const __bf16* __restrict__ A,
                                                  const __bf16* __restrict__ BT,
                                                  void* __restrict__ O0,
                                                  void* __restrict__ O1,
                                                  void* __restrict__ O2,
                                                  const float* __restrict__ FC,
                                                  const float* __restrict__ FS,
                                                  int Mt) {
  __shared__ __bf16 lds[65536];   // [2 slot][A|B][2 half][128][8 ch][8]
  const int tid = threadIdx.x;
  const int wv = tid >> 6, ln = tid & 63;
  const int lg = ln >> 4, lr = ln & 15;

  const int nwg = gridDim.x;
  const int wgid = xcd_chunk(blockIdx.x, nwg);
  const int m0 = (wgid % Mt) * 256;
  const int n0 = (wgid / Mt) * 256;
  const int wm = (wv >> 2) * 128, wn = (wv & 3) * 64;

  auto stageHalf = [&](int k, int mat, int half) {
    const int slot = k & 1;
    const int kt = k * 64;
    const __bf16* base = mat ? BT + (size_t)(n0 + half * 128) * 4096
                             : A  + (size_t)(m0 + half * 128) * 4096;
#pragma unroll
    for (int i = 0; i < 2; ++i) {
      int c = i * 512 + tid;          // chunk 0..1023
      int r = c >> 3;                 // row-in-half 0..127
      int ch = (c & 7) ^ (r & 7);     // pre-swizzled source k-chunk
      gload_lds16(base + (size_t)r * 4096 + kt + ch * 8,
                  lds + slot * 32768 + mat * 16384 + half * 8192 +
                      (i * 512 + wv * 64) * 8);
    }
  };

  f32x4 acc[8][4] = {};
  bf16x8 aLo[4][2], aHi[4][2], bLo[2][2], bHi[2][2];

  auto rdA = [&](const __bf16* pA, int mi, int kk) -> bf16x8 {
    int r = wm + mi * 16 + lr;
    int R = r & 127;
    int cw = (kk * 4 + lg) ^ (R & 7);
    return *(const bf16x8*)(pA + (r >> 7) * 8192 + R * 64 + cw * 8);
  };
  auto rdB = [&](const __bf16* pB, int ni, int kk) -> bf16x8 {
    int n = wn + ni * 16 + lr;
    int R = n & 127;
    int cw = (kk * 4 + lg) ^ (R & 7);
    return *(const bf16x8*)(pB + (n >> 7) * 8192 + R * 64 + cw * 8);
  };

  // prologue: 6 half-tiles (12 loads outstanding)
  stageHalf(0, 0, 0);
  stageHalf(0, 1, 0);
  stageHalf(0, 0, 1);
  stageHalf(0, 1, 1);
  stageHalf(1, 0, 0);
  stageHalf(1, 1, 0);

  for (int k = 0; k < 63; ++k) {
    const int slot = k & 1;
    const __bf16* pA = lds + slot * 32768;
    const __bf16* pB = lds + slot * 32768 + 16384;

    // ---- P0: stage A.hi(k+1); vmcnt(8); quad LoLo
    stageHalf(k + 1, 0, 1);
    asm volatile("s_waitcnt vmcnt(8)" ::: "memory");
    BARF();
#pragma unroll
    for (int mi = 0; mi < 4; ++mi)
#pragma unroll
      for (int kk = 0; kk < 2; ++kk) aLo[mi][kk] = rdA(pA, mi, kk);
#pragma unroll
    for (int ni = 0; ni < 2; ++ni)
#pragma unroll
      for (int kk = 0; kk < 2; ++kk) bLo[ni][kk] = rdB(pB, ni, kk);
    __builtin_amdgcn_s_setprio(1);
#pragma unroll
    for (int kk = 0; kk < 2; ++kk)
#pragma unroll
      for (int mi = 0; mi < 4; ++mi)
#pragma unroll
        for (int ni = 0; ni < 2; ++ni)
          acc[mi][ni] = mfma16(aLo[mi][kk], bLo[ni][kk], acc[mi][ni]);
    __builtin_amdgcn_s_setprio(0);
    BARF();

    // ---- P1: stage B.hi(k+1); hoisted aHi reads; vmcnt(8)
    stageHalf(k + 1, 1, 1);
#pragma unroll
    for (int mi = 0; mi < 4; ++mi)
#pragma unroll
      for (int kk = 0; kk < 2; ++kk) aHi[mi][kk] = rdA(pA, mi + 4, kk);
    asm volatile("s_waitcnt vmcnt(8)" ::: "memory");
    BARF();
    __builtin_amdgcn_s_setprio(1);
#pragma unroll
    for (int kk = 0; kk < 2; ++kk)
#pragma unroll
      for (int mi = 0; mi < 4; ++mi)
#pragma unroll
        for (int ni = 0; ni < 2; ++ni)
          acc[mi + 4][ni] = mfma16(aHi[mi][kk], bLo[ni][kk], acc[mi + 4][ni]);
    __builtin_amdgcn_s_setprio(0);
    BARF();

    // ---- P2: stage A.lo(k+2); hoisted bHi reads; quad HiHi
    if (k + 2 < 64) stageHalf(k + 2, 0, 0);
#pragma unroll
    for (int ni = 0; ni < 2; ++ni)
#pragma unroll
      for (int kk = 0; kk < 2; ++kk) bHi[ni][kk] = rdB(pB, ni + 2, kk);
    BARF();
    __builtin_amdgcn_s_setprio(1);
#pragma unroll
    for (int kk = 0; kk < 2; ++kk)
#pragma unroll
      for (int mi = 0; mi < 4; ++mi)
#pragma unroll
        for (int ni = 0; ni < 2; ++ni)
          acc[mi + 4][ni + 2] = mfma16(aHi[mi][kk], bHi[ni][kk], acc[mi + 4][ni + 2]);
    __builtin_amdgcn_s_setprio(0);
    BARF();

    // ---- P3: stage B.lo(k+2); quad LoHi (aLo registers still valid)
    if (k + 2 < 64) stageHalf(k + 2, 1, 0);
    BARF();
    __builtin_amdgcn_s_setprio(1);
#pragma unroll
    for (int kk = 0; kk < 2; ++kk)
#pragma unroll
      for (int mi = 0; mi < 4; ++mi)
#pragma unroll
        for (int ni = 0; ni < 2; ++ni)
          acc[mi][ni + 2] = mfma16(aLo[mi][kk], bHi[ni][kk], acc[mi][ni + 2]);
    __builtin_amdgcn_s_setprio(0);
    BARF();
  }

  // ---- tile 63 peeled
  {
    const __bf16* pA = lds + (63 & 1) * 32768;
    const __bf16* pB = lds + (63 & 1) * 32768 + 16384;
    asm volatile("s_waitcnt vmcnt(0)" ::: "memory");
    BARF();
#pragma unroll
    for (int mi = 0; mi < 4; ++mi)
#pragma unroll
      for (int kk = 0; kk < 2; ++kk) aLo[mi][kk] = rdA(pA, mi, kk);
#pragma unroll
    for (int ni = 0; ni < 2; ++ni)
#pragma unroll
      for (int kk = 0; kk < 2; ++kk) bLo[ni][kk] = rdB(pB, ni, kk);
#pragma unroll
    for (int kk = 0; kk < 2; ++kk)
#pragma unroll
      for (int mi = 0; mi < 4; ++mi)
#pragma unroll
        for (int ni = 0; ni < 2; ++ni)
          acc[mi][ni] = mfma16(aLo[mi][kk], bLo[ni][kk], acc[mi][ni]);
#pragma unroll
    for (int mi = 0; mi < 4; ++mi)
#pragma unroll
      for (int kk = 0; kk < 2; ++kk) aHi[mi][kk] = rdA(pA, mi + 4, kk);
#pragma unroll
    for (int ni = 0; ni < 2; ++ni)
#pragma unroll
      for (int kk = 0; kk < 2; ++kk) bHi[ni][kk] = rdB(pB, ni + 2, kk);
#pragma unroll
    for (int kk = 0; kk < 2; ++kk)
#pragma unroll
      for (int mi = 0; mi < 4; ++mi)
#pragma unroll
        for (int ni = 0; ni < 2; ++ni) {
          acc[mi + 4][ni]     = mfma16(aHi[mi][kk], bLo[ni][kk], acc[mi + 4][ni]);
          acc[mi + 4][ni + 2] = mfma16(aHi[mi][kk], bHi[ni][kk], acc[mi + 4][ni + 2]);
          acc[mi][ni + 2]     = mfma16(aLo[mi][kk], bHi[ni][kk], acc[mi][ni + 2]);
        }
  }

  // ---- epilogue
  if constexpr (MODE == 0) {
    const int sel = n0 >> 12;                 // 0=q, 1=k, 2=v
    const int colb = n0 & 4095;
    if (sel < 2) {
      // q/k: fused RoPE on f32 acc; q additionally pre-scaled by 1/sqrt(128)
      const float qs = sel ? 1.0f : 0.08838834764831845f;
      __bf16* out = sel ? (__bf16*)O1 : (__bf16*)O0;
#pragma unroll
      for (int mi = 0; mi < 8; ++mi)
#pragma unroll
        for (int j = 0; j < 4; ++j) {
          int row = m0 + wm + mi * 16 + lg * 4 + j;
          int s = row & (SEQ - 1);
#pragma unroll
          for (int ni = 0; ni < 4; ++ni) {
            int col = colb + wn + ni * 16 + lr;
            int fi = (col & 127) >> 1;
            float c  = FC[s * 64 + fi];
            float sn = FS[s * 64 + fi];
            float v = acc[mi][ni][j];
            float p = __shfl_xor(v, 1);
            float o = (lr & 1) ? (p * sn + v * c) : (v * c - p * sn);
            out[(size_t)row * 4096 + col] = (__bf16)(o * qs);
          }
        }
    } else {
      __bf16* vT = (__bf16*)O2;
#pragma unroll
      for (int mi = 0; mi < 8; ++mi) {
        int row0 = m0 + wm + mi * 16 + lg * 4;
#pragma unroll
        for (int ni = 0; ni < 4; ++ni) {
          int col = colb + wn + ni * 16 + lr;
          bf16x4 pk;
#pragma unroll
          for (int j = 0; j < 4; ++j) pk[j] = (__bf16)acc[mi][ni][j];
          *(bf16x4*)(vT + (size_t)col * MX + row0) = pk;
        }
      }
    }
  } else {
    float* out = (float*)O0;
#pragma unroll
    for (int mi = 0; mi < 8; ++mi)
#pragma unroll
      for (int ni = 0; ni < 4; ++ni)
#pragma unroll
        for (int j = 0; j < 4; ++j) {
          int row = m0 + wm + mi * 16 + lg * 4 + j;
          int col = n0 + wn + ni * 16 + lr;
          out[(size_t)row * 4096 + col] = acc[mi][ni][j];
        }
  }
}

// ---------------------------------------------------------------------------
// Adapter mini-GEMM: rows 4096..4111 = [adapter;pad] @ [wk|wv].
// K -> kb rows (no RoPE); V -> vT transposed.
__global__ __launch_bounds__(256) void gemm_adapter(const __bf16* __restrict__ xa,
                                                    const __bf16* __restrict__ BT,
                                                    __bf16* __restrict__ kb,
                                                    __bf16* __restrict__ vT) {
  const int tid = threadIdx.x;
  const int wv = tid >> 6, ln = tid & 63;
  const int lg = ln >> 4, lr = ln & 15;
  const int col0 = blockIdx.x * 256 + wv * 64;
  f32x4 acc[4] = {};
  for (int kt = 0; kt < 4096; kt += 32) {
    bf16x8 a = *(const bf16x8*)(xa + (size_t)(4096 + lr) * 4096 + kt + lg * 8);
#pragma unroll
    for (int ni = 0; ni < 4; ++ni) {
      bf16x8 b = *(const bf16x8*)(BT + (size_t)(col0 + ni * 16 + lr) * 4096 +
                                  kt + lg * 8);
      acc[ni] = mfma16(a, b, acc[ni]);
    }
  }
#pragma unroll
  for (int ni = 0; ni < 4; ++ni)
#pragma unroll
    for (int j = 0; j < 4; ++j) {
      int row = 4096 + lg * 4 + j;
      int col = col0 + ni * 16 + lr;
      if (col < 4096) kb[(size_t)row * 4096 + col] = (__bf16)acc[ni][j];
      else            vT[(size_t)(col & 4095) * MX + row] = (__bf16)acc[ni][j];
    }
}

// ---------------------------------------------------------------------------
// Flash attention + adapter. Q arrives PRE-SCALED by 1/sqrt(128) (folded
// into the QKV epilogue; rope is linear), so no scale mult here.
// Balanced pairs {qt, 15-qt}; K/V double-buffered LDS, counted vmcnt(8);
// swapped QK^T -> in-lane softmax; XCD-chunked (h,b) grouping.
__global__ __launch_bounds__(256) void attn_kernel(const __bf16* __restrict__ Q,
                                                   const __bf16* __restrict__ K,
                                                   const __bf16* __restrict__ VT,
                                                   const float* __restrict__ gate,
                                                   __bf16* __restrict__ Out) {
  __shared__ __bf16 Ks[2][64 * 128];
  __shared__ __bf16 Vs[2][128 * 64];
  __shared__ __bf16 Ps[4][32 * 64];

  const int tid = threadIdx.x;
  const int wv = tid >> 6, ln = tid & 63;
  const int lg = ln >> 4, lr = ln & 15;

  const int wgid = xcd_chunk(blockIdx.x, 512);
  const int px = wgid & 7;
  const int hb = wgid >> 3;
  const int h = hb & 31, b = hb >> 5;

  const float g = tanhf(gate[h]);

  auto stage = [&](int t, int buf) {
    const int kv0 = t * 64;
#pragma unroll
    for (int j = 0; j < 4; ++j) {
      int c = wv * 256 + j * 64 + ln;
      int rk = c >> 4, sck = (c & 15) ^ (rk & 7);
      gload_lds16(K + (size_t)(b * SEQ + kv0 + rk) * D + h * 128 + sck * 8,
                  Ks[buf] + (wv * 256 + j * 64) * 8);
      int rv = c >> 3, scv = (c & 7) ^ (rv & 7);
      gload_lds16(VT + (size_t)(h * 128 + rv) * MX + b * SEQ + kv0 + scv * 8,
                  Vs[buf] + (wv * 256 + j * 64) * 8);
    }
  };

  auto run_supertile = [&](int qt) {
    const int q0 = qt * 128;
    const int qbase = b * SEQ + q0 + wv * 32;

    bf16x8 qf[2][4];
#pragma unroll
    for (int mi = 0; mi < 2; ++mi)
#pragma unroll
      for (int kd = 0; kd < 4; ++kd)
        qf[mi][kd] = *(const bf16x8*)(Q + (size_t)(qbase + mi * 16 + lr) * D +
                                      h * 128 + kd * 32 + lg * 8);

    f32x4 O[2][8] = {};
    float mI2[2], lI2[2];
#pragma unroll
    for (int mi = 0; mi < 2; ++mi) { mI2[mi] = -1e30f; lI2[mi] = 0.f; }

    const int ntiles = 2 * qt + 2;
    stage(0, 0);

    for (int t = 0; t < ntiles; ++t) {
      const int cur = t & 1;
      const int kv0 = t * 64;
      if (t + 1 < ntiles) {
        stage(t + 1, cur ^ 1);
        asm volatile("s_waitcnt vmcnt(8)" ::: "memory");
      } else {
        asm volatile("s_waitcnt vmcnt(0)" ::: "memory");
      }
      __builtin_amdgcn_s_barrier();
      __builtin_amdgcn_sched_barrier(0);

      f32x4 S[2][4] = {};
      __builtin_amdgcn_s_setprio(1);
#pragma unroll
      for (int kd = 0; kd < 4; ++kd) {
        bf16x8 kf[4];
#pragma unroll
        for (int nf = 0; nf < 4; ++nf) {
          int kr = nf * 16 + lr;
          kf[nf] = *(const bf16x8*)(Ks[cur] + kr * 128 +
                                    (((kd * 4 + lg) ^ (kr & 7)) * 8));
        }
#pragma unroll
        for (int mi = 0; mi < 2; ++mi)
#pragma unroll
          for (int nf = 0; nf < 4; ++nf)
            S[mi][nf] = mfma16(kf[nf], qf[mi][kd], S[mi][nf]);
      }
      __builtin_amdgcn_s_setprio(0);

      float r2[2]; int grew = 0;
#pragma unroll
      for (int mi = 0; mi < 2; ++mi) {
        const int qg = q0 + wv * 32 + mi * 16 + lr;
        float mo = mI2[mi];
        float mt = -3e38f;
#pragma unroll
        for (int nf = 0; nf < 4; ++nf)
#pragma unroll
          for (int j = 0; j < 4; ++j) {
            int kvg = kv0 + nf * 16 + lg * 4 + j;
            float s = S[mi][nf][j];
            s = (kvg > qg) ? -1e30f : s;
            S[mi][nf][j] = s;
            mt = fmaxf(mt, s);
          }
        mt = fmaxf(mt, __shfl_xor(mt, 16));
        mt = fmaxf(mt, __shfl_xor(mt, 32));
        float mn = fmaxf(mo, mt);
        float ps = 0.f;
#pragma unroll
        for (int nf = 0; nf < 4; ++nf)
#pragma unroll
          for (int j = 0; j < 4; ++j) {
            float p = __expf(S[mi][nf][j] - mn);
            S[mi][nf][j] = p;
            ps += p;
          }
        ps += __shfl_xor(ps, 16);
        ps += __shfl_xor(ps, 32);
        float r = __expf(mo - mn);
        lI2[mi] = lI2[mi] * r + ps;
        mI2[mi] = mn;
        r2[mi] = r;
        grew |= (mn > mo) ? 1 : 0;
      }
      if (__any(grew)) {
#pragma unroll
        for (int mi = 0; mi < 2; ++mi)
#pragma unroll
          for (int j = 0; j < 4; ++j) {
            float rj = __shfl(r2[mi], lg * 4 + j);
#pragma unroll
            for (int n = 0; n < 8; ++n) O[mi][n][j] *= rj;
          }
      }

      // P -> bf16x4 packed stores
#pragma unroll
      for (int mi = 0; mi < 2; ++mi) {
        int q = mi * 16 + lr;
#pragma unroll
        for (int nf = 0; nf < 4; ++nf) {
          int kv = nf * 16 + lg * 4;
          bf16x4 pk;
#pragma unroll
          for (int j = 0; j < 4; ++j) pk[j] = (__bf16)S[mi][nf][j];
          *(bf16x4*)(Ps[wv] + q * 64 + (((kv >> 3) ^ (q & 7)) * 8) + (kv & 7)) = pk;
        }
      }

      __builtin_amdgcn_s_setprio(1);
#pragma unroll
      for (int kkv = 0; kkv < 2; ++kkv) {
        bf16x8 pf[2];
#pragma unroll
        for (int mi = 0; mi < 2; ++mi) {
          int prw = mi * 16 + lr;
          pf[mi] = *(const bf16x8*)(Ps[wv] + prw * 64 +
                                    (((kkv * 4 + lg) ^ (prw & 7)) * 8));
        }
#pragma unroll
        for (int n = 0; n < 8; ++n) {
          int vr = n * 16 + lr;
          bf16x8 vf = *(const bf16x8*)(Vs[cur] + vr * 64 +
                                       (((kkv * 4 + lg) ^ (vr & 7)) * 8));
#pragma unroll
          for (int mi = 0; mi < 2; ++mi) O[mi][n] = mfma16(pf[mi], vf, O[mi][n]);
        }
      }
      __builtin_amdgcn_s_setprio(0);

      __builtin_amdgcn_s_barrier();
      __builtin_amdgcn_sched_barrier(0);
    }

#pragma unroll
    for (int mi = 0; mi < 2; ++mi) {
      float inv = 1.0f / lI2[mi];
#pragma unroll
      for (int j = 0; j < 4; ++j) {
        float invj = __shfl(inv, lg * 4 + j);
#pragma unroll
        for (int n = 0; n < 8; ++n) O[mi][n][j] *= invj;
      }
    }

    {
      f32x4 Sa[2] = {};
#pragma unroll
      for (int kd = 0; kd < 4; ++kd) {
        bf16x8 kfa = *(const bf16x8*)(K + (size_t)(2 * SEQ + lr) * D +
                                      h * 128 + kd * 32 + lg * 8);
#pragma unroll
        for (int mi = 0; mi < 2; ++mi) Sa[mi] = mfma16(kfa, qf[mi][kd], Sa[mi]);
      }
#pragma unroll
      for (int mi = 0; mi < 2; ++mi) {
        float mt = -3e38f;
#pragma unroll
        for (int j = 0; j < 4; ++j) {
          int kv = lg * 4 + j;
          float s = Sa[mi][j];
          s = (kv >= 10) ? -1e30f : s;
          Sa[mi][j] = s;
          mt = fmaxf(mt, s);
        }
        mt = fmaxf(mt, __shfl_xor(mt, 16));
        mt = fmaxf(mt, __shfl_xor(mt, 32));
        float ps = 0.f;
#pragma unroll
        for (int j = 0; j < 4; ++j) {
          float p = __expf(Sa[mi][j] - mt);
          Sa[mi][j] = p;
          ps += p;
        }
        ps += __shfl_xor(ps, 16);
        ps += __shfl_xor(ps, 32);
        float gs = g / ps;
        int q = mi * 16 + lr;
        int kv = lg * 4;
        bf16x4 pk, z = {};
#pragma unroll
        for (int j = 0; j < 4; ++j) pk[j] = (__bf16)(Sa[mi][j] * gs);
        *(bf16x4*)(Ps[wv] + q * 64 + (((kv >> 3) ^ (q & 7)) * 8) + (kv & 7)) = pk;
        int kv2 = 16 + kv;
        *(bf16x4*)(Ps[wv] + q * 64 + (((kv2 >> 3) ^ (q & 7)) * 8) + (kv2 & 7)) = z;
      }
      bf16x8 pfa[2];
#pragma unroll
      for (int mi = 0; mi < 2; ++mi) {
        int prw = mi * 16 + lr;
        pfa[mi] = *(const bf16x8*)(Ps[wv] + prw * 64 + ((lg ^ (prw & 7)) * 8));
      }
#pragma unroll
      for (int n = 0; n < 8; ++n) {
        bf16x8 vfa = *(const bf16x8*)(VT + (size_t)(h * 128 + n * 16 + lr) * MX +
                                      2 * SEQ + lg * 8);
#pragma unroll
        for (int mi = 0; mi < 2; ++mi) O[mi][n] = mfma16(pfa[mi], vfa, O[mi][n]);
      }
    }

#pragma unroll
    for (int mi = 0; mi < 2; ++mi)
#pragma unroll
      for (int n = 0; n < 8; ++n)
#pragma unroll
        for (int j = 0; j < 4; ++j)
          Out[(size_t)(qbase + mi * 16 + lg * 4 + j) * D + h * 128 + n * 16 + lr] =
              (__bf16)O[mi][n][j];
  };

  run_supertile(15 - px);
  run_supertile(px);
}

// ---------------------------------------------------------------------------
extern "C" void kernel_launch(void* const* d_in, const int* in_sizes, int n_in,
                              void* d_out, int out_size, void* d_ws, size_t ws_size,
                              hipStream_t stream) {
  const float* x    = (const float*)d_in[0];
  const float* wq   = (const float*)d_in[1];
  const float* wk   = (const float*)d_in[2];
  const float* wv   = (const float*)d_in[3];
  const float* wo   = (const float*)d_in[4];
  const float* gate = (const float*)d_in[5];
  const float* ad   = (const float*)d_in[6];
  const float* fc   = (const float*)d_in[7];
  const float* fs   = (const float*)d_in[8];

  const size_t WSZ = (size_t)D * D * 2;     // 33,554,432
  const size_t XSZ = (size_t)MX * D * 2;    // 34,603,008
  if (ws_size < 4 * WSZ + XSZ + WSZ + 3 * XSZ) return;  // 306,184,192 needed

  char* w = (char*)d_ws;
  size_t off = 0;
  auto alloc = [&](size_t sz) { void* p = w + off; off += sz; return p; };
  __bf16* wqT = (__bf16*)alloc(WSZ);   // wqT/wkT/wvT contiguous = fused 12288xK B^T
  __bf16* wkT = (__bf16*)alloc(WSZ);
  __bf16* wvT = (__bf16*)alloc(WSZ);
  __bf16* woT = (__bf16*)alloc(WSZ);
  __bf16* xa  = (__bf16*)alloc(XSZ);
  __bf16* qb  = (__bf16*)alloc(WSZ);
  __bf16* kb  = (__bf16*)alloc(XSZ);
  __bf16* vb  = (__bf16*)alloc(XSZ);   // scratch; used as attention output
  __bf16* vT  = (__bf16*)alloc(XSZ);
  __bf16* attn = vb;
  (void)wvT;

  dim3 blk(256);
  transpose_cast4<<<dim3(64, 64, 4), blk, 0, stream>>>(wq, wk, wv, wo, wqT);
  build_xa<<<dim3(16896), blk, 0, stream>>>(x, ad, xa);

  // fused QKV GEMM (rope+qscale fused q/k, transposed v): 16x48 = 768 = 3x256.
  gemm256<0><<<dim3(16 * 48), dim3(512), 0, stream>>>(xa, wqT, qb, kb, vT,
                                                      fc, fs, 16);
  // adapter rows 4096..4111: K -> kb rows (no RoPE), V -> vT transposed.
  gemm_adapter<<<dim3(32), blk, 0, stream>>>(xa, wkT, kb, vT);

  attn_kernel<<<dim3(512), blk, 0, stream>>>(qb, kb, vT, gate, attn);

  gemm256<1><<<dim3(16 * 16), dim3(512), 0, stream>>>(attn, woT, d_out,
                                                      nullptr, nullptr,
                                                      nullptr, nullptr, 16);
}